// Round 1
// 111.705 us; speedup vs baseline: 1.0370x; 1.0370x over previous
//
#include <hip/hip_runtime.h>
#include <hip/hip_fp16.h>

#define BATCH 2048

typedef _Float16 f16x8 __attribute__((ext_vector_type(8)));
typedef float f32x4 __attribute__((ext_vector_type(4)));

// fast sigmoid: v_fma/v_mul + v_exp_f32 + v_add + v_rcp_f32 (~1ulp, tol 0.125)
__device__ __forceinline__ float fast_sigmoid(float v) {
    return __builtin_amdgcn_rcpf(1.0f + __builtin_amdgcn_exp2f(v * -1.44269504f));
}

// ---------------------------------------------------------------------------
// Workspace layout (bytes):
//   [0      .. 301056)  W3B  tree B-frags f16 [gi 21][c 14][lane 64][8h]
//                       value for k = c*32 + (lane>>4)*8 + u, f = lane&15,
//                       k order: k = u27*16 + nn, u27 = tt*4+q2 = ki*14 + pw
//                       (j=pw>>1, kj=pw&1), nn = channel-in-group (15 -> 0)
//   [301056 .. 314496)  FCW2 f32 [g 3][o 10][i 7][f 16]
// ---------------------------------------------------------------------------
#define WS_W3B  0
#define WS_FCW  301056

__global__ __launch_bounds__(256) void k_prep(
    const float* __restrict__ tree_w,
    const float* __restrict__ fc_w,
    ushort* __restrict__ W3B,
    float* __restrict__ FCW2,
    float* __restrict__ out)
{
    int pidx = blockIdx.x * 256 + threadIdx.x;
    if (pidx < 20480) out[pidx] = 0.f;      // fold output zeroing (was memset)
    if (pidx < 18816) {                     // W3B: 21*14*64 uint4
        int gi = pidx / 896;
        int rem = pidx - gi * 896;
        int c = rem >> 6, lane2 = rem & 63;
        int f = lane2 & 15, qq = lane2 >> 4;
        int g = gi / 7, i = gi - g * 7;
        ushort h[8];
        #pragma unroll
        for (int u = 0; u < 8; u++) {
            int k = c * 32 + qq * 8 + u;    // 0..447
            int tt = k >> 6;
            int q2 = (k >> 4) & 3;
            int nn = k & 15;
            int u27 = tt * 4 + q2;          // 0..27
            int ki = u27 / 14;
            int pw = u27 - ki * 14;
            int j = pw >> 1, kj = pw & 1;
            float v = 0.f;
            if (nn < 15)
                v = tree_w[(size_t)f * 8820 + nn * 588 + g * 196 + i * 28
                           + j * 4 + ki * 2 + kj];
            h[u] = __half_as_ushort(__float2half(v));
        }
        *(uint4*)(W3B + (size_t)pidx * 8) = *(uint4*)h;
    } else if (pidx < 22176) {              // FCW2: 3*10*7*16 f32
        int j = pidx - 18816;
        int f = j & 15;
        int r = j >> 4;
        int i = r % 7;
        int r2 = r / 7;
        int o = r2 % 10;
        int g = r2 / 10;
        FCW2[j] = fc_w[o * 336 + f * 21 + g * 7 + i];
    }
}

// ---------------------------------------------------------------------------
// kF_all: per (image-quad, g). Conv in 2 rounds of 2 images (xsc reused),
// tree einsum with M=4 images per MFMA (lane&3 -> image), FC over 4 waves.
// LDS: xsc 2x4656 (18,624 B) + ps 4x3192 (25,536 B) + tsl 896 B = 45,056 B
//   -> 3 blocks/CU (135 KiB of 160).
// ---------------------------------------------------------------------------
__global__ __launch_bounds__(256, 3) void kF_all(
    const float* __restrict__ x,       // [B][3][32][32]
    const float* __restrict__ conv_w,  // [45][25]
    const float* __restrict__ conv_b,  // [45]
    const ushort* __restrict__ W3B,
    const float* __restrict__ FCW2,    // [3][10][7][16] f32
    const float* __restrict__ tree_b,  // [336]
    const float* __restrict__ fc_b,    // [10]
    float* __restrict__ out)           // [2048][10] (zeroed by k_prep)
{
    __shared__ __align__(16) ushort xsc[2 * 4656];
    __shared__ __align__(16) ushort ps[4 * 3192];   // [im4][i 7][456]
    __shared__ __align__(16) ushort tsl[28 * 16];   // [m=im4*7+i][f]

    const int tid  = threadIdx.x;
    const int blk  = blockIdx.x;
    const int quad = blk / 3;
    const int g    = blk - quad * 3;
    const int img0 = quad * 4;
    const int lane = tid & 63;
    const int n    = lane & 15;
    const int q    = lane >> 4;
    const int wave = tid >> 6;

    // ---- issue all 4 images' channel-g plane loads early ----
    float4 xv[4];
    #pragma unroll
    for (int im = 0; im < 4; im++)
        xv[im] = ((const float4*)(x + (size_t)(img0 + im) * 3072 + g * 1024))[tid];

    // ---- conv B-frags + folded bias (bs = -bias*log2(e)) ----
    f16x8 B1 = {0, 0, 0, 0, 0, 0, 0, 0};
    f16x8 B2 = {0, 0, 0, 0, 0, 0, 0, 0};
    float bs = 0.f;
    if (n < 15) {
        const float* wrow = conv_w + (g * 15 + n) * 25;
        #pragma unroll
        for (int u = 0; u < 5; u++) B1[u] = (_Float16)wrow[q * 5 + u];
        if (q == 0) {
            #pragma unroll
            for (int u = 0; u < 5; u++) B2[u] = (_Float16)wrow[20 + u];
        }
        bs = conv_b[g * 15 + n] * -1.44269504f;
    }

    // ---- hoisted per-wave tile offsets (img- and round-independent) ----
    const int dr = (n >> 1) & 1, dc = n & 1, n4 = n >> 2;
    const int a2c = 144 - q * 36;      // A1 base -> row r+4
    int aoff[13], svr[13];
    #pragma unroll
    for (int it = 0; it < 13; it++) {
        int t = wave + it * 4;         // it<12 always <49; it==12 only wave 0
        int pb = t * 4 + n4;
        int ph = pb / 14, pw = pb - ph * 14;
        int r = 2 * ph + dr, c = 2 * pw + dc;
        int s = c & 3;
        aoff[it] = s * 1164 + (r + q) * 36 + (c - s);
        int i = t / 7, tt = t - i * 7;
        svr[it] = i * 456 + tt * 64 + lane;     // LDS ps offset
    }

    // ---- phase-2 per-thread indices: one divide, reused every round ----
    const int rowA = tid / 9, g4A = tid - rowA * 9;          // item tid
    const int vB   = tid + 256;
    const int rowB = vB / 9,  g4B = vB - rowB * 9;           // tail (tid<32)

    // 3 shifted copies from one load pair; shared shift subexpressions
    auto do_shift = [&](int row, int g4) {
        #pragma unroll
        for (int im2 = 0; im2 < 2; im2++) {
            ushort* sp = xsc + im2 * 4656 + row * 36 + g4 * 4;
            if (g4 == 8) {
                uint2 z = make_uint2(0u, 0u);
                *(uint2*)(sp + 1164) = z;
                *(uint2*)(sp + 2328) = z;
                *(uint2*)(sp + 3492) = z;
            } else {
                uint2 lo = *(const uint2*)sp;
                uint2 hi = *(const uint2*)(sp + 4);
                unsigned w0 = lo.x, w1 = lo.y, w2 = hi.x, w3 = hi.y;
                unsigned t01 = (w0 >> 16) | (w1 << 16);   // cols +1,+2
                unsigned t12 = (w1 >> 16) | (w2 << 16);   // cols +3,+4
                unsigned t23 = (w2 >> 16) | (w3 << 16);   // cols +5,+6
                *(uint2*)(sp + 1164) = make_uint2(t01, t12);  // s=1
                *(uint2*)(sp + 2328) = make_uint2(w1, w2);    // s=2
                *(uint2*)(sp + 3492) = make_uint2(t12, t23);  // s=3
            }
        }
    };

    auto conv_tile = [&](int it, const ushort* xb, ushort* pso) {
        const ushort* pA = xb + aoff[it];
        union { struct { uint2 a, b; } u; f16x8 v; } A1, A2;
        A1.u.a = *(const uint2*)pA;
        A1.u.b = *(const uint2*)(pA + 4);
        A2.u.a = *(const uint2*)(pA + a2c);
        A2.u.b = *(const uint2*)(pA + a2c + 4);
        f32x4 d = {0.f, 0.f, 0.f, 0.f};
        d = __builtin_amdgcn_mfma_f32_16x16x32_f16(A1.v, B1, d, 0, 0, 0);
        d = __builtin_amdgcn_mfma_f32_16x16x32_f16(A2.v, B2, d, 0, 0, 0);
        float mx = fmaxf(fmaxf(d[0], d[1]), fmaxf(d[2], d[3]));
        // n==15 lanes: B=0 -> mx=0, bs=0 -> store 0.5; W3B nn==15 weight is 0,
        // so the garbage lane never reaches the output (select dropped).
        float e = __builtin_amdgcn_exp2f(fmaf(mx, -1.44269504f, bs));
        float val = __builtin_amdgcn_rcpf(1.0f + e);
        pso[svr[it]] = __half_as_ushort(__float2half(val));
    };

    // ---- 2 rounds x 2 images: pack -> shift copies -> conv+pool -> ps ----
    #pragma unroll
    for (int r2 = 0; r2 < 2; r2++) {
        #pragma unroll
        for (int im2 = 0; im2 < 2; im2++) {    // phase 1: f16 pack, stride 36
            float4 v = xv[r2 * 2 + im2];
            int row = tid >> 3, col = (tid & 7) * 4;
            __half2 a = __float22half2_rn(make_float2(v.x, v.y));
            __half2 b = __float22half2_rn(make_float2(v.z, v.w));
            uint2 pk;
            pk.x = *(unsigned int*)&a;
            pk.y = *(unsigned int*)&b;
            *(uint2*)(xsc + im2 * 4656 + row * 36 + col) = pk;
        }
        if (tid < 64) {                        // zero cols 32..35 of copy0
            int im2 = tid >> 5, r = tid & 31;
            *(uint2*)(xsc + im2 * 4656 + r * 36 + 32) = make_uint2(0u, 0u);
        }
        __syncthreads();

        do_shift(rowA, g4A);                   // phase 2: shifted copies s=1..3
        if (tid < 32) do_shift(rowB, g4B);
        __syncthreads();

        #pragma unroll
        for (int im2 = 0; im2 < 2; im2++) {    // conv main
            const ushort* xb = xsc + im2 * 4656;
            ushort* pso = ps + (r2 * 2 + im2) * 3192;
            #pragma unroll
            for (int it = 0; it < 12; it++) conv_tile(it, xb, pso);
            if (wave == 0) conv_tile(12, xb, pso);
        }
        __syncthreads();                       // ps done / xsc reusable
    }

    // ---- tree: 7 per-i GEMMs over waves; M=4 images via lane&3 ----
    for (int ii = wave; ii < 7; ii += 4) {
        const f16x8* Wb = (const f16x8*)W3B + (size_t)(g * 7 + ii) * 896;
        const ushort* ap = ps + (n & 3) * 3192 + ii * 456;
        f16x8 Bf[14];
        #pragma unroll
        for (int c = 0; c < 14; c++) Bf[c] = Wb[c * 64 + lane];
        f32x4 D0 = {0.f, 0.f, 0.f, 0.f};
        f32x4 D1 = {0.f, 0.f, 0.f, 0.f};
        #pragma unroll
        for (int c = 0; c < 7; c++) {
            f16x8 Ae = *(const f16x8*)(ap + (2 * c) * 32 + q * 8);
            D0 = __builtin_amdgcn_mfma_f32_16x16x32_f16(Ae, Bf[2 * c], D0, 0, 0, 0);
            f16x8 Ao = *(const f16x8*)(ap + (2 * c + 1) * 32 + q * 8);
            D1 = __builtin_amdgcn_mfma_f32_16x16x32_f16(Ao, Bf[2 * c + 1], D1, 0, 0, 0);
        }
        if (q == 0) {                  // rows 0..3 = images 0..3
            float tb = tree_b[n * 21 + g * 7 + ii];
            #pragma unroll
            for (int im = 0; im < 4; im++) {
                float t = (D0[im] + D1[im]) + tb;
                tsl[(im * 7 + ii) * 16 + n] =
                    __half_as_ushort(__float2half(fast_sigmoid(t)));
            }
        }
    }
    __syncthreads();

    // ---- partial FC: wave w handles image w, lanes 0..9 = o; atomic add ----
    if (lane < 10) {
        const int im4 = wave, o = lane;
        const uint2* tp = (const uint2*)(tsl + im4 * 112);
        const float4* wp = (const float4*)(FCW2 + (size_t)(g * 10 + o) * 112);
        float acc = (g == 0) ? fc_b[o] : 0.f;
        #pragma unroll
        for (int jj = 0; jj < 28; jj++) {
            float4 w4 = wp[jj];
            uint2 hv = tp[jj];
            float2 p0 = __half22float2(*(const __half2*)&hv.x);
            float2 p1 = __half22float2(*(const __half2*)&hv.y);
            acc = fmaf(p0.x, w4.x, acc);
            acc = fmaf(p0.y, w4.y, acc);
            acc = fmaf(p1.x, w4.z, acc);
            acc = fmaf(p1.y, w4.w, acc);
        }
#if defined(__HIP_PLATFORM_AMD__)
        unsafeAtomicAdd(out + (size_t)(img0 + im4) * 10 + o, acc);
#else
        atomicAdd(out + (size_t)(img0 + im4) * 10 + o, acc);
#endif
    }
}

extern "C" void kernel_launch(void* const* d_in, const int* in_sizes, int n_in,
                              void* d_out, int out_size, void* d_ws, size_t ws_size,
                              hipStream_t stream) {
    const float* x      = (const float*)d_in[0];
    const float* conv_w = (const float*)d_in[1];
    const float* conv_b = (const float*)d_in[2];
    const float* tree_w = (const float*)d_in[3];
    const float* tree_b = (const float*)d_in[4];
    const float* fc_w   = (const float*)d_in[5];
    const float* fc_b   = (const float*)d_in[6];
    float* out = (float*)d_out;

    ushort* W3B  = (ushort*)((char*)d_ws + WS_W3B);
    float*  FCW2 = (float*)((char*)d_ws + WS_FCW);

    k_prep<<<87, 256, 0, stream>>>(tree_w, fc_w, W3B, FCW2, out);
    kF_all<<<512 * 3, 256, 0, stream>>>(x, conv_w, conv_b, W3B, FCW2,
                                        tree_b, fc_b, out);
}

// Round 2
// 110.794 us; speedup vs baseline: 1.0455x; 1.0082x over previous
//
#include <hip/hip_runtime.h>
#include <hip/hip_fp16.h>

#define BATCH 2048

typedef _Float16 f16x8 __attribute__((ext_vector_type(8)));
typedef float f32x4 __attribute__((ext_vector_type(4)));

// LDS geometry: chosen so conv A-read start-banks tile all 32 banks exactly
// 4-deep (the wave64 b64 floor):  CST/2 % 32 == 8 (copy term period 4 slots)
// and RST/4 == 9 (odd -> row term uniform mod 4).  8B alignment preserved.
#define RST 36        // xsc row stride (ushorts)
#define CST 1168      // xsc shifted-copy stride: 32*36 + 16
#define IMS 4672      // xsc image stride = 4*CST
#define IST 448       // ps i stride (7 tt * 64)
#define PIS 3152      // ps image stride: 7*448 + 16  (PIS/2 % 32 == 8)

__device__ __forceinline__ float fast_sigmoid(float v) {
    return __builtin_amdgcn_rcpf(1.0f + __builtin_amdgcn_exp2f(v * -1.44269504f));
}

// ---------------------------------------------------------------------------
// Workspace layout (bytes):
//   [0      .. 301056)  W3B  tree B-frags f16 [gi 21][c 14][lane 64][8h]
//                       k = c*32 + qq*8 + u  (qq=lane>>4, f=lane&15)
//                       u27 = k>>4 = ki*14 + j*2 + kj, nn = k&15 (15 -> 0)
//   [301056 .. 314496)  FCW2 f32 [g 3][o 10][i 7][f 16]
// ---------------------------------------------------------------------------
#define WS_W3B  0
#define WS_FCW  301056

// k_prep v2: coalesced float4 read of tree_w + scattered 2B stores (no load
// latency chain).  4 consecutive elements share (f,nn,g,i,j), vary (ki,kj).
__global__ __launch_bounds__(256) void k_prep(
    const float* __restrict__ tree_w,
    const float* __restrict__ fc_w,
    ushort* __restrict__ W3B,
    float* __restrict__ FCW2,
    float* __restrict__ out)
{
    int pidx = blockIdx.x * 256 + threadIdx.x;
    if (pidx < 35280) {                     // W3B scatter: 141120 f32 / 4
        float4 v = ((const float4*)tree_w)[pidx];
        int j  = pidx % 7;                  // idx=4*pidx: j=(idx>>2)%7
        int t1 = pidx / 7;
        int i  = t1 % 7;
        int t2 = t1 / 7;
        int g  = t2 % 3;
        int t3 = t2 / 3;
        int nn = t3 % 15;
        int f  = t3 / 15;
        int gi = g * 7 + i;
        int u  = nn & 7;
        int hi = nn >> 3;
        float vv[4] = {v.x, v.y, v.z, v.w};
        #pragma unroll
        for (int e = 0; e < 4; e++) {
            int ki = e >> 1, kj = e & 1;
            int u27 = ki * 14 + j * 2 + kj;
            int c   = u27 >> 1;
            int qq  = (u27 & 1) * 2 + hi;
            W3B[(size_t)(gi * 14 + c) * 512 + (qq * 16 + f) * 8 + u] =
                __half_as_ushort(__float2half(vv[e]));
        }
    } else if (pidx < 38640) {              // FCW2: 3*10*7*16 f32
        int jj = pidx - 35280;
        int f = jj & 15;
        int r = jj >> 4;
        int i = r % 7;
        int r2 = r / 7;
        int o = r2 % 10;
        int g = r2 / 10;
        FCW2[jj] = fc_w[o * 336 + f * 21 + g * 7 + i];
    } else if (pidx < 48048) {              // zero the nn==15 slots (qq odd, u=7)
        int z = pidx - 38640;
        int f  = z & 15;
        int qq = ((z >> 4) & 1) * 2 + 1;
        int r  = z >> 5;
        int c  = r % 14;
        int gi = r / 14;
        W3B[(size_t)(gi * 14 + c) * 512 + (qq * 16 + f) * 8 + 7] = 0;
    } else if (pidx < 68528) {              // zero out[2048][10]
        out[pidx - 48048] = 0.f;
    }
}

// ---------------------------------------------------------------------------
// kF_all: per (image-quad, g). Conv in 2 rounds of 2 images; pack+shifted
// copies fused via __shfl_down (no LDS->LDS shift phase, 5 barriers total);
// conv tiles process both images together (8 ds_reads in flight, 2 indep
// MFMA chains); tree einsum M=4 images; FC over 4 waves.
// LDS: xsc 18,688 + ps 25,216 + tsl 896 = 44,800 B -> 3 blocks/CU.
// ---------------------------------------------------------------------------
__global__ __launch_bounds__(256, 3) void kF_all(
    const float* __restrict__ x,       // [B][3][32][32]
    const float* __restrict__ conv_w,  // [45][25]
    const float* __restrict__ conv_b,  // [45]
    const ushort* __restrict__ W3B,
    const float* __restrict__ FCW2,    // [3][10][7][16] f32
    const float* __restrict__ tree_b,  // [336]
    const float* __restrict__ fc_b,    // [10]
    float* __restrict__ out)           // [2048][10] (zeroed by k_prep)
{
    __shared__ __align__(16) ushort xsc[2 * IMS];
    __shared__ __align__(16) ushort ps[4 * PIS];    // [im4][i 7][tt 7][64]
    __shared__ __align__(16) ushort tsl[28 * 16];   // [m=im4*7+i][f]

    const int tid  = threadIdx.x;
    const int blk  = blockIdx.x;
    const int quad = blk / 3;
    const int g    = blk - quad * 3;
    const int img0 = quad * 4;
    const int lane = tid & 63;
    const int n    = lane & 15;
    const int q    = lane >> 4;
    const int wave = tid >> 6;

    // ---- issue all 4 images' channel-g plane loads early ----
    float4 xv[4];
    #pragma unroll
    for (int im = 0; im < 4; im++)
        xv[im] = ((const float4*)(x + (size_t)(img0 + im) * 3072 + g * 1024))[tid];

    // ---- conv B-frags + folded bias (bs = -bias*log2(e)) ----
    f16x8 B1 = {0, 0, 0, 0, 0, 0, 0, 0};
    f16x8 B2 = {0, 0, 0, 0, 0, 0, 0, 0};
    float bs = 0.f;
    if (n < 15) {
        const float* wrow = conv_w + (g * 15 + n) * 25;
        #pragma unroll
        for (int u = 0; u < 5; u++) B1[u] = (_Float16)wrow[q * 5 + u];
        if (q == 0) {
            #pragma unroll
            for (int u = 0; u < 5; u++) B2[u] = (_Float16)wrow[20 + u];
        }
        bs = conv_b[g * 15 + n] * -1.44269504f;
    }

    // ---- hoisted per-wave tile offsets (img- and round-independent) ----
    const int dr = (n >> 1) & 1, dc = n & 1, n4 = n >> 2;
    const int a2c = (4 - q) * RST;     // A1 base (row r+q) -> row r+4
    int aoff[13], svr[13];
    #pragma unroll
    for (int it = 0; it < 13; it++) {
        int t = wave + it * 4;         // it<12 always <49; it==12 only wave 0
        int pb = t * 4 + n4;
        int ph = pb / 14, pw = pb - ph * 14;
        int r = 2 * ph + dr, c = 2 * pw + dc;
        int s = c & 3;
        aoff[it] = s * CST + (r + q) * RST + (c - s);
        int i = t / 7, tt = t - i * 7;
        svr[it] = i * IST + tt * 64 + lane;     // ps offset (per image)
    }

    // conv tile: both images of the round, interleaved MFMA chains
    auto conv_tile2 = [&](int it, ushort* pso) {
        const ushort* pA0 = xsc + aoff[it];
        const ushort* pA1 = pA0 + IMS;
        union U { struct { uint2 a, b; } u; f16x8 v; };
        U A1a, A2a, A1b, A2b;
        A1a.u.a = *(const uint2*)pA0;
        A1a.u.b = *(const uint2*)(pA0 + 4);
        A2a.u.a = *(const uint2*)(pA0 + a2c);
        A2a.u.b = *(const uint2*)(pA0 + a2c + 4);
        A1b.u.a = *(const uint2*)pA1;
        A1b.u.b = *(const uint2*)(pA1 + 4);
        A2b.u.a = *(const uint2*)(pA1 + a2c);
        A2b.u.b = *(const uint2*)(pA1 + a2c + 4);
        f32x4 da = {0.f, 0.f, 0.f, 0.f}, db = {0.f, 0.f, 0.f, 0.f};
        da = __builtin_amdgcn_mfma_f32_16x16x32_f16(A1a.v, B1, da, 0, 0, 0);
        db = __builtin_amdgcn_mfma_f32_16x16x32_f16(A1b.v, B1, db, 0, 0, 0);
        da = __builtin_amdgcn_mfma_f32_16x16x32_f16(A2a.v, B2, da, 0, 0, 0);
        db = __builtin_amdgcn_mfma_f32_16x16x32_f16(A2b.v, B2, db, 0, 0, 0);
        float mxa = fmaxf(fmaxf(da[0], da[1]), fmaxf(da[2], da[3]));
        float mxb = fmaxf(fmaxf(db[0], db[1]), fmaxf(db[2], db[3]));
        // n==15 lanes produce 0.5 garbage; W3B nn==15 weight is 0 downstream.
        float ea = __builtin_amdgcn_exp2f(fmaf(mxa, -1.44269504f, bs));
        float eb = __builtin_amdgcn_exp2f(fmaf(mxb, -1.44269504f, bs));
        pso[svr[it]] =
            __half_as_ushort(__float2half(__builtin_amdgcn_rcpf(1.0f + ea)));
        pso[PIS + svr[it]] =
            __half_as_ushort(__float2half(__builtin_amdgcn_rcpf(1.0f + eb)));
    };

    // ---- 2 rounds x 2 images: fused pack+shift -> conv+pool -> ps ----
    const int row = tid >> 3, colg = (tid & 7) * 4;
    #pragma unroll
    for (int r2 = 0; r2 < 2; r2++) {
        #pragma unroll
        for (int im2 = 0; im2 < 2; im2++) {
            float4 v = xv[r2 * 2 + im2];
            __half2 a = __float22half2_rn(make_float2(v.x, v.y));
            __half2 b = __float22half2_rn(make_float2(v.z, v.w));
            unsigned d0 = *(unsigned*)&a, d1 = *(unsigned*)&b;
            unsigned n0 = (unsigned)__shfl_down((int)d0, 1);  // cols +4,+5
            unsigned n1 = (unsigned)__shfl_down((int)d1, 1);  // cols +6,+7
            if ((tid & 7) == 7) { n0 = 0u; n1 = 0u; }  // x cols 32..34 = 0
            unsigned t01 = (d0 >> 16) | (d1 << 16);    // cols +1,+2
            unsigned t12 = (d1 >> 16) | (n0 << 16);    // cols +3,+4
            unsigned t23 = (n0 >> 16) | (n1 << 16);    // cols +5,+6
            ushort* base = xsc + im2 * IMS + row * RST + colg;
            *(uint2*)(base)           = make_uint2(d0, d1);    // s=0
            *(uint2*)(base + CST)     = make_uint2(t01, t12);  // s=1
            *(uint2*)(base + 2 * CST) = make_uint2(d1, n0);    // s=2
            *(uint2*)(base + 3 * CST) = make_uint2(t12, t23);  // s=3
        }
        __syncthreads();

        ushort* pso = ps + (r2 * 2) * PIS;
        #pragma unroll
        for (int it = 0; it < 12; it++) conv_tile2(it, pso);
        if (wave == 0) conv_tile2(12, pso);
        __syncthreads();                       // ps done / xsc reusable
    }

    // ---- tree: 7 per-i GEMMs over waves; M=4 images via lane&3 ----
    for (int ii = wave; ii < 7; ii += 4) {
        const f16x8* Wb = (const f16x8*)W3B + (size_t)(g * 7 + ii) * 896;
        const ushort* ap = ps + (n & 3) * PIS + ii * IST;
        f16x8 Bf[14];
        #pragma unroll
        for (int c = 0; c < 14; c++) Bf[c] = Wb[c * 64 + lane];
        f32x4 D0 = {0.f, 0.f, 0.f, 0.f};
        f32x4 D1 = {0.f, 0.f, 0.f, 0.f};
        #pragma unroll
        for (int c = 0; c < 7; c++) {
            f16x8 Ae = *(const f16x8*)(ap + (2 * c) * 32 + q * 8);
            D0 = __builtin_amdgcn_mfma_f32_16x16x32_f16(Ae, Bf[2 * c], D0, 0, 0, 0);
            f16x8 Ao = *(const f16x8*)(ap + (2 * c + 1) * 32 + q * 8);
            D1 = __builtin_amdgcn_mfma_f32_16x16x32_f16(Ao, Bf[2 * c + 1], D1, 0, 0, 0);
        }
        if (q == 0) {                  // rows 0..3 = images 0..3
            float tb = tree_b[n * 21 + g * 7 + ii];
            #pragma unroll
            for (int im = 0; im < 4; im++) {
                float t = (D0[im] + D1[im]) + tb;
                tsl[(im * 7 + ii) * 16 + n] =
                    __half_as_ushort(__float2half(fast_sigmoid(t)));
            }
        }
    }
    __syncthreads();

    // ---- partial FC: wave w handles image w, lanes 0..9 = o; atomic add ----
    if (lane < 10) {
        const int im4 = wave, o = lane;
        const uint2* tp = (const uint2*)(tsl + im4 * 112);
        const float4* wp = (const float4*)(FCW2 + (size_t)(g * 10 + o) * 112);
        float acc = (g == 0) ? fc_b[o] : 0.f;
        #pragma unroll
        for (int jj = 0; jj < 28; jj++) {
            float4 w4 = wp[jj];
            uint2 hv = tp[jj];
            float2 p0 = __half22float2(*(const __half2*)&hv.x);
            float2 p1 = __half22float2(*(const __half2*)&hv.y);
            acc = fmaf(p0.x, w4.x, acc);
            acc = fmaf(p0.y, w4.y, acc);
            acc = fmaf(p1.x, w4.z, acc);
            acc = fmaf(p1.y, w4.w, acc);
        }
#if defined(__HIP_PLATFORM_AMD__)
        unsafeAtomicAdd(out + (size_t)(img0 + im4) * 10 + o, acc);
#else
        atomicAdd(out + (size_t)(img0 + im4) * 10 + o, acc);
#endif
    }
}

extern "C" void kernel_launch(void* const* d_in, const int* in_sizes, int n_in,
                              void* d_out, int out_size, void* d_ws, size_t ws_size,
                              hipStream_t stream) {
    const float* x      = (const float*)d_in[0];
    const float* conv_w = (const float*)d_in[1];
    const float* conv_b = (const float*)d_in[2];
    const float* tree_w = (const float*)d_in[3];
    const float* tree_b = (const float*)d_in[4];
    const float* fc_w   = (const float*)d_in[5];
    const float* fc_b   = (const float*)d_in[6];
    float* out = (float*)d_out;

    ushort* W3B  = (ushort*)((char*)d_ws + WS_W3B);
    float*  FCW2 = (float*)((char*)d_ws + WS_FCW);

    k_prep<<<268, 256, 0, stream>>>(tree_w, fc_w, W3B, FCW2, out);
    kF_all<<<512 * 3, 256, 0, stream>>>(x, conv_w, conv_b, W3B, FCW2,
                                        tree_b, fc_b, out);
}

// Round 3
// 102.262 us; speedup vs baseline: 1.1328x; 1.0834x over previous
//
#include <hip/hip_runtime.h>
#include <hip/hip_fp16.h>

#define BATCH 2048

typedef _Float16 f16x8 __attribute__((ext_vector_type(8)));
typedef float f32x4 __attribute__((ext_vector_type(4)));

// xsc geometry (dwords): 2 planes only (s=0 even-shift, s=1 odd-shift);
// shifts 2,3 are dword-offset reads of planes 0,1 (4B-aligned pair loads).
#define XROW 18       // row stride (dwords): 16 data + 2 pad (dword16 zeroed)
#define XPL  584      // plane stride: 32*18 + 8  (%32 == 8 for bank spread)
#define XIMG 1168     // image stride = 2 planes
#define PIS  3152     // ps image stride (ushorts): 49*64 + 16 (/2 %32 == 8)

__device__ __forceinline__ float fast_sigmoid(float v) {
    return __builtin_amdgcn_rcpf(1.0f + __builtin_amdgcn_exp2f(v * -1.44269504f));
}

// ---------------------------------------------------------------------------
// Workspace layout (bytes):
//   [0      .. 301056)  W3B  tree B-frags f16 [gi 21][c 14][lane 64][8h]
//   [301056 .. 314496)  FCW2 f32 [g 3][o 10][i 7][f 16]
// ---------------------------------------------------------------------------
#define WS_W3B  0
#define WS_FCW  301056

// k_prep: coalesced float4 read of tree_w + scattered 2B stores.
__global__ __launch_bounds__(256) void k_prep(
    const float* __restrict__ tree_w,
    const float* __restrict__ fc_w,
    ushort* __restrict__ W3B,
    float* __restrict__ FCW2,
    float* __restrict__ out)
{
    int pidx = blockIdx.x * 256 + threadIdx.x;
    if (pidx < 35280) {                     // W3B scatter: 141120 f32 / 4
        float4 v = ((const float4*)tree_w)[pidx];
        int j  = pidx % 7;
        int t1 = pidx / 7;
        int i  = t1 % 7;
        int t2 = t1 / 7;
        int g  = t2 % 3;
        int t3 = t2 / 3;
        int nn = t3 % 15;
        int f  = t3 / 15;
        int gi = g * 7 + i;
        int u  = nn & 7;
        int hi = nn >> 3;
        float vv[4] = {v.x, v.y, v.z, v.w};
        #pragma unroll
        for (int e = 0; e < 4; e++) {
            int ki = e >> 1, kj = e & 1;
            int u27 = ki * 14 + j * 2 + kj;
            int c   = u27 >> 1;
            int qq  = (u27 & 1) * 2 + hi;
            W3B[(size_t)(gi * 14 + c) * 512 + (qq * 16 + f) * 8 + u] =
                __half_as_ushort(__float2half(vv[e]));
        }
    } else if (pidx < 38640) {              // FCW2: 3*10*7*16 f32
        int jj = pidx - 35280;
        int f = jj & 15;
        int r = jj >> 4;
        int i = r % 7;
        int r2 = r / 7;
        int o = r2 % 10;
        int g = r2 / 10;
        FCW2[jj] = fc_w[o * 336 + f * 21 + g * 7 + i];
    } else if (pidx < 48048) {              // zero nn==15 slots (qq odd, u=7)
        int z = pidx - 38640;
        int f  = z & 15;
        int qq = ((z >> 4) & 1) * 2 + 1;
        int r  = z >> 5;
        int c  = r % 14;
        int gi = r / 14;
        W3B[(size_t)(gi * 14 + c) * 512 + (qq * 16 + f) * 8 + 7] = 0;
    } else if (pidx < 68528) {              // zero out[2048][10]
        out[pidx - 48048] = 0.f;
    }
}

// ---------------------------------------------------------------------------
// kF_all: per (image-quad, g). 2-plane xsc (9,344 B) + ps (25,216 B), tsl
// aliased into dead xsc -> 34,560 B LDS -> 4 blocks/CU (16 waves, +33% TLP
// vs r2).  Conv A-frags read with dword-granular offsets (planes 0/1 cover
// all 4 column shifts).  svr array removed (ps offset = 64*t + lane); aoff
// table built with a wrap-recurrence (no divides).
// ---------------------------------------------------------------------------
__global__ __launch_bounds__(256, 4) void kF_all(
    const float* __restrict__ x,       // [B][3][32][32]
    const float* __restrict__ conv_w,  // [45][25]
    const float* __restrict__ conv_b,  // [45]
    const ushort* __restrict__ W3B,
    const float* __restrict__ FCW2,    // [3][10][7][16] f32
    const float* __restrict__ tree_b,  // [336]
    const float* __restrict__ fc_b,    // [10]
    float* __restrict__ out)           // [2048][10] (zeroed by k_prep)
{
    __shared__ __align__(16) unsigned xsc[2 * XIMG];  // 9,344 B
    __shared__ __align__(16) ushort ps[4 * PIS];      // 25,216 B
    ushort* tsl = (ushort*)xsc;        // [28][16], alias (xsc dead after conv)

    const int tid  = threadIdx.x;
    const int blk  = blockIdx.x;
    const int quad = blk / 3;
    const int g    = blk - quad * 3;
    const int img0 = quad * 4;
    const int lane = tid & 63;
    const int n    = lane & 15;
    const int q    = lane >> 4;
    const int wave = tid >> 6;

    // ---- issue all 4 images' channel-g plane loads early ----
    float4 xv[4];
    #pragma unroll
    for (int im = 0; im < 4; im++)
        xv[im] = ((const float4*)(x + (size_t)(img0 + im) * 3072 + g * 1024))[tid];

    // ---- zero pad dwords 16,17 of every row/plane/image (written once;
    //      data packs only touch dwords 0..15, so pads persist) ----
    if (tid < 128) {
        int im = tid >> 6, pl = (tid >> 5) & 1, row = tid & 31;
        *(uint2*)&xsc[im * XIMG + pl * XPL + row * XROW + 16] = make_uint2(0u, 0u);
    }

    // ---- conv B-frags + folded bias (bs = -bias*log2(e)) ----
    f16x8 B1 = {0, 0, 0, 0, 0, 0, 0, 0};
    f16x8 B2 = {0, 0, 0, 0, 0, 0, 0, 0};
    float bs = 0.f;
    if (n < 15) {
        const float* wrow = conv_w + (g * 15 + n) * 25;
        #pragma unroll
        for (int u = 0; u < 5; u++) B1[u] = (_Float16)wrow[q * 5 + u];
        if (q == 0) {
            #pragma unroll
            for (int u = 0; u < 5; u++) B2[u] = (_Float16)wrow[20 + u];
        }
        bs = conv_b[g * 15 + n] * -1.44269504f;
    }

    // ---- per-lane conv A offsets (dwords), wrap-recurrence, no divides ----
    const int dr = (n >> 1) & 1, dc = n & 1, n4 = n >> 2;
    const int a2cd = (4 - q) * XROW;   // row r+q -> row r+4
    int aoffd[13];
    {
        int pb = wave * 4 + n4;        // 0..15
        int ph = (pb >= 14) ? 1 : 0;
        int pw = pb - 14 * ph;
        int base = dc * XPL + (dr + q) * XROW;
        #pragma unroll
        for (int it = 0; it < 13; it++) {
            aoffd[it] = base + 2 * ph * XROW + pw;   // + dword col (c>>1 == pw)
            pw += 2; ph += 1;
            if (pw >= 14) { pw -= 14; ph += 1; }
        }
    }

    // ---- fused pack: plane0 {d0,d1}, plane1 {t01,t12} ----
    const int prow = tid >> 3, pt = tid & 7;
    auto pack_img = [&](int im2, float4 v) {
        __half2 a = __float22half2_rn(make_float2(v.x, v.y));
        __half2 b = __float22half2_rn(make_float2(v.z, v.w));
        unsigned d0 = *(unsigned*)&a, d1 = *(unsigned*)&b;
        unsigned n0 = (unsigned)__shfl_down((int)d0, 1);
        if (pt == 7) n0 = 0u;                       // col 32 = 0
        unsigned t01 = (d0 >> 16) | (d1 << 16);     // cols +1,+2
        unsigned t12 = (d1 >> 16) | (n0 << 16);     // cols +3,+4
        unsigned* base = xsc + im2 * XIMG + prow * XROW + 2 * pt;
        *(uint2*)(base)       = make_uint2(d0, d1);
        *(uint2*)(base + XPL) = make_uint2(t01, t12);
    };

    // ---- conv tile: both images of the round, interleaved MFMA chains ----
    auto conv_tile2 = [&](int it, ushort* pso) {
        const unsigned* p0 = xsc + aoffd[it];
        const unsigned* p1 = p0 + XIMG;
        union U { unsigned w[4]; f16x8 v; };
        U A1a, A2a, A1b, A2b;
        #pragma unroll
        for (int e = 0; e < 4; e++) {
            A1a.w[e] = p0[e];
            A2a.w[e] = p0[a2cd + e];
            A1b.w[e] = p1[e];
            A2b.w[e] = p1[a2cd + e];
        }
        f32x4 da = {0.f, 0.f, 0.f, 0.f}, db = {0.f, 0.f, 0.f, 0.f};
        da = __builtin_amdgcn_mfma_f32_16x16x32_f16(A1a.v, B1, da, 0, 0, 0);
        db = __builtin_amdgcn_mfma_f32_16x16x32_f16(A1b.v, B1, db, 0, 0, 0);
        da = __builtin_amdgcn_mfma_f32_16x16x32_f16(A2a.v, B2, da, 0, 0, 0);
        db = __builtin_amdgcn_mfma_f32_16x16x32_f16(A2b.v, B2, db, 0, 0, 0);
        float mxa = fmaxf(fmaxf(da[0], da[1]), fmaxf(da[2], da[3]));
        float mxb = fmaxf(fmaxf(db[0], db[1]), fmaxf(db[2], db[3]));
        float ea = __builtin_amdgcn_exp2f(fmaf(mxa, -1.44269504f, bs));
        float eb = __builtin_amdgcn_exp2f(fmaf(mxb, -1.44269504f, bs));
        int so = (wave + it * 4) * 64 + lane;   // ps offset = 64*t + lane
        pso[so] =
            __half_as_ushort(__float2half(__builtin_amdgcn_rcpf(1.0f + ea)));
        pso[PIS + so] =
            __half_as_ushort(__float2half(__builtin_amdgcn_rcpf(1.0f + eb)));
    };

    // ---- 2 rounds x 2 images: pack -> conv+pool -> ps ----
    #pragma unroll
    for (int r2 = 0; r2 < 2; r2++) {
        pack_img(0, xv[r2 * 2 + 0]);
        pack_img(1, xv[r2 * 2 + 1]);
        __syncthreads();

        ushort* pso = ps + (r2 * 2) * PIS;
        #pragma unroll
        for (int it = 0; it < 12; it++) conv_tile2(it, pso);
        if (wave == 0) conv_tile2(12, pso);
        __syncthreads();                       // ps done / xsc reusable
    }

    // ---- tree: 7 per-i GEMMs over waves; M=4 images via lane&3 ----
    for (int ii = wave; ii < 7; ii += 4) {
        const f16x8* Wb = (const f16x8*)W3B + (size_t)(g * 7 + ii) * 896;
        const ushort* ap = ps + (n & 3) * PIS + ii * 448;
        f16x8 Bf[14];
        #pragma unroll
        for (int c = 0; c < 14; c++) Bf[c] = Wb[c * 64 + lane];
        f32x4 D0 = {0.f, 0.f, 0.f, 0.f};
        f32x4 D1 = {0.f, 0.f, 0.f, 0.f};
        #pragma unroll
        for (int c = 0; c < 7; c++) {
            f16x8 Ae = *(const f16x8*)(ap + (2 * c) * 32 + q * 8);
            D0 = __builtin_amdgcn_mfma_f32_16x16x32_f16(Ae, Bf[2 * c], D0, 0, 0, 0);
            f16x8 Ao = *(const f16x8*)(ap + (2 * c + 1) * 32 + q * 8);
            D1 = __builtin_amdgcn_mfma_f32_16x16x32_f16(Ao, Bf[2 * c + 1], D1, 0, 0, 0);
        }
        if (q == 0) {                  // rows 0..3 = images 0..3
            float tb = tree_b[n * 21 + g * 7 + ii];
            #pragma unroll
            for (int im = 0; im < 4; im++) {
                float t = (D0[im] + D1[im]) + tb;
                tsl[(im * 7 + ii) * 16 + n] =
                    __half_as_ushort(__float2half(fast_sigmoid(t)));
            }
        }
    }
    __syncthreads();

    // ---- partial FC: wave w handles image w, lanes 0..9 = o; atomic add ----
    if (lane < 10) {
        const int im4 = wave, o = lane;
        const uint2* tp = (const uint2*)(tsl + im4 * 112);
        const float4* wp = (const float4*)(FCW2 + (size_t)(g * 10 + o) * 112);
        float acc = (g == 0) ? fc_b[o] : 0.f;
        #pragma unroll
        for (int jj = 0; jj < 28; jj++) {
            float4 w4 = wp[jj];
            uint2 hv = tp[jj];
            float2 p0 = __half22float2(*(const __half2*)&hv.x);
            float2 p1 = __half22float2(*(const __half2*)&hv.y);
            acc = fmaf(p0.x, w4.x, acc);
            acc = fmaf(p0.y, w4.y, acc);
            acc = fmaf(p1.x, w4.z, acc);
            acc = fmaf(p1.y, w4.w, acc);
        }
#if defined(__HIP_PLATFORM_AMD__)
        unsafeAtomicAdd(out + (size_t)(img0 + im4) * 10 + o, acc);
#else
        atomicAdd(out + (size_t)(img0 + im4) * 10 + o, acc);
#endif
    }
}

extern "C" void kernel_launch(void* const* d_in, const int* in_sizes, int n_in,
                              void* d_out, int out_size, void* d_ws, size_t ws_size,
                              hipStream_t stream) {
    const float* x      = (const float*)d_in[0];
    const float* conv_w = (const float*)d_in[1];
    const float* conv_b = (const float*)d_in[2];
    const float* tree_w = (const float*)d_in[3];
    const float* tree_b = (const float*)d_in[4];
    const float* fc_w   = (const float*)d_in[5];
    const float* fc_b   = (const float*)d_in[6];
    float* out = (float*)d_out;

    ushort* W3B  = (ushort*)((char*)d_ws + WS_W3B);
    float*  FCW2 = (float*)((char*)d_ws + WS_FCW);

    k_prep<<<268, 256, 0, stream>>>(tree_w, fc_w, W3B, FCW2, out);
    kF_all<<<512 * 3, 256, 0, stream>>>(x, conv_w, conv_b, W3B, FCW2,
                                        tree_b, fc_b, out);
}